// Round 19
// baseline (215.646 us; speedup 1.0000x reference)
//
#include <hip/hip_runtime.h>

// LSTM B=4096, S=512, INPUT=1, HIDDEN=20 + linear head.
// R17: R16 (one ACT per wave, validated: 572 cyc/step, predicted 500-580)
// x 2 groups per block.  R16 post-mortem: SIMD0 (2 streams, 224 trans
// issue) and SIMD1-3 (1 stream, 112 issue + ~450 EXPOSED residual) are
// equally critical -> single-stream SIMDs waste ~450 cyc of hideable
// latency.  Merge two 16-chain groups into one 768-thread block (12 waves,
// 32 chains, 128 blocks): every SIMD gets 3 streams, ACT quantization over
// 4 SIMDs = {3,2,3,2} ACTs = max 21 trans = 336 cyc issue (provably minimal
// for 10 ACT waves), residual hidden by the 3-way interleave (R15b measured
// the marginal stream at ~100 cyc).  Expect ~430-500 cyc/step for 32 chains
// -> ~95-117 us chip time.
// Per-group structure byte-identical to R16 (verified absmax 9.77e-4):
// waves wg=0..4 own gate-mfma m=wg + dense ACT; wg=5 owns head mfma +
// one-step-skewed y store + epilogue.  A row 4Q+r = gate r of unit 5Q+m,
// k-slot s = unit 5q+s (s<5); C col=lane&15, row=4*(lane>>4)+reg;
// x*W_ih+bias via f32 C-operand; fused-reciprocal ACT (5 exp2 + 2 rcp),
// c >= -34; RS=44 stride, 2xb64 h reads.

#define BATCH 4096
#define SLEN  512
#define H     20
#define RS    44     // hrow stride in halfs (22 words: spread write banks)
#define LOG2E 1.44269504088896340736f

typedef _Float16 f16x8 __attribute__((ext_vector_type(8)));
typedef _Float16 f16x4 __attribute__((ext_vector_type(4)));
typedef float    f32x4 __attribute__((ext_vector_type(4)));

__device__ __forceinline__ float fexp2(float x) { return __builtin_amdgcn_exp2f(x); }
__device__ __forceinline__ float frcp(float x)  { return __builtin_amdgcn_rcpf(x); }

// one unit's activations (R11b/R13/R16-verified): Cv = [i,f,g,o] pre-scaled
#define ACT(Cv, CC, HV) {                                             \
    const float eI = fexp2((Cv)[0]);                                  \
    const float eF = fexp2((Cv)[1]);                                  \
    const float eG = fexp2((Cv)[2]);                                  \
    const float eO = fexp2((Cv)[3]);                                  \
    const float pF = 1.0f + eF;                                       \
    const float P  = (1.0f + eI) * (1.0f + eG);                       \
    const float num = fmaf(CC, P, (1.0f - eG) * pF);                  \
    CC = fmaxf(num * frcp(pF * P), -34.0f);                           \
    const float eC = fexp2(s2 * CC);                                  \
    HV = (1.0f - eC) * frcp((1.0f + eO) * (1.0f + eC));               \
}

__global__ __launch_bounds__(768, 1) void lstm_fused(
    const float* __restrict__ x,      // [B, S, 1]
    const float* __restrict__ W_ih,   // [80, 1]
    const float* __restrict__ W_hh,   // [80, 20]
    const float* __restrict__ b_ih,   // [80]
    const float* __restrict__ b_hh,   // [80]
    const float* __restrict__ W_lin,  // [1, 20]
    const float* __restrict__ b_lin,  // [1]
    float* __restrict__ out)          // [B, S, 1]
{
    __shared__ __align__(16) _Float16 hrow[2][2][16][RS];  // [group][parity][chain][slots]

    const int tid  = threadIdx.x;
    const int wv   = tid >> 6;          // wave 0..11
    const int g    = (wv >= 6) ? 1 : 0; // chain group
    const int wg   = wv - 6 * g;        // within-group role 0..5
    const int lane = tid & 63;
    const int q    = lane >> 4;         // k-group / unit-block 0..3
    const int n    = lane & 15;         // chain column (dense)
    const long b   = (long)blockIdx.x * 32 + g * 16 + n;   // 128*32 = 4096

    const float s1 = -LOG2E;            // sigmoid pre-scale
    const float s2 = -2.0f * LOG2E;     // tanh pre-scale

    const bool isgate = (wg < 5);       // roles 0..4: gate mfma m=wg + ACT
    const bool ishead = (wg == 5);      // role 5: head mfma + y store
    const int  m     = isgate ? wg : 0;

    // ---- A fragment (f16): row n -> gate gA of unit uA+m; k-slot s =
    // unit 5q+s (s<5), slots 5-7 zero ----
    const int gA = n & 3;
    const int uA = (n >> 2) * 5;
    const float scA = (gA == 2) ? s2 : s1;   // torch gate order i,f,g,o
    f16x8 am;
    {
        const int row = gA * H + uA + m;
#pragma unroll
        for (int s = 0; s < 8; ++s)
            am[s] = (_Float16)((s < 5) ? scA * W_hh[row * H + 5 * q + s] : 0.0f);
    }
    // head A: row 0 = W_lin; b_lin via C-input
    f16x8 ah;
#pragma unroll
    for (int s = 0; s < 8; ++s)
        ah[s] = (_Float16)((n == 0 && s < 5) ? W_lin[5 * q + s] : 0.0f);
    const f32x4 chi = {(q == 0) ? b_lin[0] : 0.0f, 0.0f, 0.0f, 0.0f};

    // ---- f32 C-init constants for the owned unit (gate waves) ----
    f32x4 xw, bb;
#pragma unroll
    for (int r = 0; r < 4; ++r) {
        const float sc = (r == 2) ? s2 : s1;
        const int row = r * H + 5 * q + m;
        xw[r] = sc * W_ih[row];
        bb[r] = sc * (b_ih[row] + b_hh[row]);
    }

    const float* xb = x + b * SLEN;
    float*       ob = out + b * SLEN;

    // zero both groups/parities (h(-1)=0 in parity 1): 1408 words
    for (int i = tid; i < 2 * 2 * 16 * RS / 2; i += 768) ((unsigned*)hrow)[i] = 0u;
    __syncthreads();

    float cc = 0.0f;                 // c state of owned unit (gate waves)
    f32x4 ya;                        // head wave: y quad (one-step skew)
    f32x4 xc = *(const f32x4*)xb;    // current x quad

#define STEP(p)                                                            \
    {                                                                      \
        f16x8 bf;                                                          \
        {                                                                  \
            const _Float16* hp_ = &hrow[g][((p) & 1) ^ 1][n][8 * q];       \
            const f16x4 lo_ = *(const f16x4*)hp_;                          \
            const f16x4 hi_ = *(const f16x4*)(hp_ + 4);                    \
            bf = __builtin_shufflevector(lo_, hi_, 0, 1, 2, 3, 4, 5, 6, 7); \
        }                                                                  \
        if (ishead) {                                                      \
            const f32x4 Ch =                                               \
                __builtin_amdgcn_mfma_f32_16x16x32_f16(ah, bf, chi, 0, 0, 0); \
            const float yv = Ch[0];            /* y(t-1), t = 4k+p */      \
            if ((p) == 0) {                                                \
                ya[3] = yv;                                                \
                if (k > 0 && lane < 16) *(f32x4*)(ob + 4 * k - 4) = ya;    \
            } else if ((p) == 1) ya[0] = yv;                               \
            else if ((p) == 2) ya[1] = yv;                                 \
            else ya[2] = yv;                                               \
        }                                                                  \
        if (isgate) {                                                      \
            const float xt = xc[(p)];                                      \
            f32x4 ci;                                                      \
            ci[0] = fmaf(xt, xw[0], bb[0]);                                \
            ci[1] = fmaf(xt, xw[1], bb[1]);                                \
            ci[2] = fmaf(xt, xw[2], bb[2]);                                \
            ci[3] = fmaf(xt, xw[3], bb[3]);                                \
            f32x4 C0 = __builtin_amdgcn_mfma_f32_16x16x32_f16(am, bf, ci, 0, 0, 0); \
            float hv;                                                      \
            ACT(C0, cc, hv);                                               \
            hrow[g][(p) & 1][n][8 * q + m] = (_Float16)hv;                 \
        }                                                                  \
        __syncthreads();                                                   \
    }

#pragma unroll 1
    for (int k = 0; k < 128; ++k) {
        const int t0 = 4 * k;
        const int tn = (t0 + 4 < SLEN) ? t0 + 4 : SLEN - 4;   // clamp
        const f32x4 xn = *(const f32x4*)(xb + tn);            // prefetch

        STEP(0) STEP(1) STEP(2) STEP(3)

        xc = xn;
    }
#undef STEP

    // epilogue: y(511) from h(511) (parity 1, published by last barrier)
    if (ishead) {
        const _Float16* hp_ = &hrow[g][1][n][8 * q];
        const f16x4 lo_ = *(const f16x4*)hp_;
        const f16x4 hi_ = *(const f16x4*)(hp_ + 4);
        const f16x8 bf = __builtin_shufflevector(lo_, hi_, 0, 1, 2, 3, 4, 5, 6, 7);
        const f32x4 Ch = __builtin_amdgcn_mfma_f32_16x16x32_f16(ah, bf, chi, 0, 0, 0);
        ya[3] = Ch[0];
        if (lane < 16) *(f32x4*)(ob + SLEN - 4) = ya;
    }
}

extern "C" void kernel_launch(void* const* d_in, const int* in_sizes, int n_in,
                              void* d_out, int out_size, void* d_ws, size_t ws_size,
                              hipStream_t stream) {
    const float* x     = (const float*)d_in[0];
    const float* W_ih  = (const float*)d_in[1];
    const float* W_hh  = (const float*)d_in[2];
    const float* b_ih  = (const float*)d_in[3];
    const float* b_hh  = (const float*)d_in[4];
    const float* W_lin = (const float*)d_in[5];
    const float* b_lin = (const float*)d_in[6];
    float* out = (float*)d_out;

    const int nblocks = BATCH / 32;   // 128 blocks x 12 waves (2 dense groups)
    lstm_fused<<<nblocks, 768, 0, stream>>>(x, W_ih, W_hh, b_ih, b_hh,
                                            W_lin, b_lin, out);
}

// Round 20
// 187.309 us; speedup vs baseline: 1.1513x; 1.1513x over previous
//
#include <hip/hip_runtime.h>

// LSTM B=4096, S=512, INPUT=1, HIDDEN=20 + linear head.
// R18: R16 (validated best: 122us, 572 cyc/step) with the head role merged
// into wave 1 -> 5 waves / 320 threads.  Session model (R13/R15b/R16/R17
// all fit): wall = max-per-SIMD trans-pipe time (16 cyc/wave-op) + exposed
// latency/barrier overhead.  R16: max-SIMD = {m0,m4} = 14 trans = 224 cyc
// + ~350 overhead.  5 dense ACT waves is trans-optimal (320 unit-ACTs/64
// lanes); 5 on 4 SIMDs forces max=2 ACTs/SIMD -> 224 is the issue floor at
// full chip (16 chains/CU; 2-group variants halve CU count and lose: R17).
// This round trims overhead: 6->5 barrier participants (less convoy
// stagger), one fewer wave's bookkeeping.  Rejected by analysis: b128 h
// reads (RS=0 mod 8 degrades read banks to ~8-way; RS=44 + 2xb64 spreads
// over 16 banks), ACT splitting (needs mid-step barrier), setprio (no
// role-diverse SIMD pair left to arbitrate).
// Numerics byte-identical to R16 (verified absmax 9.77e-4): A row 4Q+r =
// gate r of unit 5Q+m, k-slot s = unit 5q+s (s<5); C col=lane&15,
// row=4*(lane>>4)+reg; x*W_ih+bias via f32 C-operand; fused-reciprocal ACT
// (5 exp2 + 2 rcp), c >= -34; head one-step skew + epilogue; RS=44.
// Roles: wv0..4 own gate-mfma m=wv + dense ACT; wv1 ALSO owns head mfma +
// y store.  SIMD trans load {14, 7, 7, 7} (S0 = {wv0, wv4}).

#define BATCH 4096
#define SLEN  512
#define H     20
#define RS    44     // hrow stride in halfs (22 words: spread write banks)
#define LOG2E 1.44269504088896340736f

typedef _Float16 f16x8 __attribute__((ext_vector_type(8)));
typedef _Float16 f16x4 __attribute__((ext_vector_type(4)));
typedef float    f32x4 __attribute__((ext_vector_type(4)));

__device__ __forceinline__ float fexp2(float x) { return __builtin_amdgcn_exp2f(x); }
__device__ __forceinline__ float frcp(float x)  { return __builtin_amdgcn_rcpf(x); }

// one unit's activations (R11b/R13/R16-verified): Cv = [i,f,g,o] pre-scaled
#define ACT(Cv, CC, HV) {                                             \
    const float eI = fexp2((Cv)[0]);                                  \
    const float eF = fexp2((Cv)[1]);                                  \
    const float eG = fexp2((Cv)[2]);                                  \
    const float eO = fexp2((Cv)[3]);                                  \
    const float pF = 1.0f + eF;                                       \
    const float P  = (1.0f + eI) * (1.0f + eG);                       \
    const float num = fmaf(CC, P, (1.0f - eG) * pF);                  \
    CC = fmaxf(num * frcp(pF * P), -34.0f);                           \
    const float eC = fexp2(s2 * CC);                                  \
    HV = (1.0f - eC) * frcp((1.0f + eO) * (1.0f + eC));               \
}

__global__ __launch_bounds__(320, 1) void lstm_fused(
    const float* __restrict__ x,      // [B, S, 1]
    const float* __restrict__ W_ih,   // [80, 1]
    const float* __restrict__ W_hh,   // [80, 20]
    const float* __restrict__ b_ih,   // [80]
    const float* __restrict__ b_hh,   // [80]
    const float* __restrict__ W_lin,  // [1, 20]
    const float* __restrict__ b_lin,  // [1]
    float* __restrict__ out)          // [B, S, 1]
{
    __shared__ __align__(16) _Float16 hrow[2][16][RS];   // [parity][chain][slots]

    const int tid  = threadIdx.x;
    const int wv   = tid >> 6;          // wave 0..4
    const int lane = tid & 63;
    const int q    = lane >> 4;         // k-group / unit-block 0..3
    const int n    = lane & 15;         // chain column (dense)
    const long b   = (long)blockIdx.x * 16 + n;   // 256*16 = 4096 exact

    const float s1 = -LOG2E;            // sigmoid pre-scale
    const float s2 = -2.0f * LOG2E;     // tanh pre-scale

    const int  m      = wv;             // owned gate-mfma / ACT
    const bool ishead = (wv == 1);      // wv1 also owns head mfma + y store

    // ---- A fragment (f16): row n -> gate gA of unit uA+m; k-slot s =
    // unit 5q+s (s<5), slots 5-7 zero ----
    const int gA = n & 3;
    const int uA = (n >> 2) * 5;
    const float scA = (gA == 2) ? s2 : s1;   // torch gate order i,f,g,o
    f16x8 am;
    {
        const int row = gA * H + uA + m;
#pragma unroll
        for (int s = 0; s < 8; ++s)
            am[s] = (_Float16)((s < 5) ? scA * W_hh[row * H + 5 * q + s] : 0.0f);
    }
    // head A: row 0 = W_lin; b_lin via C-input
    f16x8 ah;
#pragma unroll
    for (int s = 0; s < 8; ++s)
        ah[s] = (_Float16)((n == 0 && s < 5) ? W_lin[5 * q + s] : 0.0f);
    const f32x4 chi = {(q == 0) ? b_lin[0] : 0.0f, 0.0f, 0.0f, 0.0f};

    // ---- f32 C-init constants for the owned unit ----
    f32x4 xw, bb;
#pragma unroll
    for (int r = 0; r < 4; ++r) {
        const float sc = (r == 2) ? s2 : s1;
        const int row = r * H + 5 * q + m;
        xw[r] = sc * W_ih[row];
        bb[r] = sc * (b_ih[row] + b_hh[row]);
    }

    const float* xb = x + b * SLEN;
    float*       ob = out + b * SLEN;

    // zero both parities (h(-1)=0 in parity 1): 2*16*RS halfs = 704 words
    for (int i = tid; i < 2 * 16 * RS / 2; i += 320) ((unsigned*)hrow)[i] = 0u;
    __syncthreads();

    float cc = 0.0f;                 // c state of owned unit
    f32x4 ya;                        // head role: y quad (one-step skew)
    f32x4 xc = *(const f32x4*)xb;    // current x quad

#define STEP(p)                                                            \
    {                                                                      \
        f16x8 bf;                                                          \
        {                                                                  \
            const _Float16* hp_ = &hrow[((p) & 1) ^ 1][n][8 * q];          \
            const f16x4 lo_ = *(const f16x4*)hp_;                          \
            const f16x4 hi_ = *(const f16x4*)(hp_ + 4);                    \
            bf = __builtin_shufflevector(lo_, hi_, 0, 1, 2, 3, 4, 5, 6, 7); \
        }                                                                  \
        if (ishead) {                                                      \
            const f32x4 Ch =                                               \
                __builtin_amdgcn_mfma_f32_16x16x32_f16(ah, bf, chi, 0, 0, 0); \
            const float yv = Ch[0];            /* y(t-1), t = 4k+p */      \
            if ((p) == 0) {                                                \
                ya[3] = yv;                                                \
                if (k > 0 && lane < 16) *(f32x4*)(ob + 4 * k - 4) = ya;    \
            } else if ((p) == 1) ya[0] = yv;                               \
            else if ((p) == 2) ya[1] = yv;                                 \
            else ya[2] = yv;                                               \
        }                                                                  \
        {                                                                  \
            const float xt = xc[(p)];                                      \
            f32x4 ci;                                                      \
            ci[0] = fmaf(xt, xw[0], bb[0]);                                \
            ci[1] = fmaf(xt, xw[1], bb[1]);                                \
            ci[2] = fmaf(xt, xw[2], bb[2]);                                \
            ci[3] = fmaf(xt, xw[3], bb[3]);                                \
            f32x4 C0 = __builtin_amdgcn_mfma_f32_16x16x32_f16(am, bf, ci, 0, 0, 0); \
            float hv;                                                      \
            ACT(C0, cc, hv);                                               \
            hrow[(p) & 1][n][8 * q + m] = (_Float16)hv;                    \
        }                                                                  \
        __syncthreads();                                                   \
    }

#pragma unroll 1
    for (int k = 0; k < 128; ++k) {
        const int t0 = 4 * k;
        const int tn = (t0 + 4 < SLEN) ? t0 + 4 : SLEN - 4;   // clamp
        const f32x4 xn = *(const f32x4*)(xb + tn);            // prefetch

        STEP(0) STEP(1) STEP(2) STEP(3)

        xc = xn;
    }
#undef STEP

    // epilogue: y(511) from h(511) (parity 1, published by last barrier)
    if (ishead) {
        const _Float16* hp_ = &hrow[1][n][8 * q];
        const f16x4 lo_ = *(const f16x4*)hp_;
        const f16x4 hi_ = *(const f16x4*)(hp_ + 4);
        const f16x8 bf = __builtin_shufflevector(lo_, hi_, 0, 1, 2, 3, 4, 5, 6, 7);
        const f32x4 Ch = __builtin_amdgcn_mfma_f32_16x16x32_f16(ah, bf, chi, 0, 0, 0);
        ya[3] = Ch[0];
        if (lane < 16) *(f32x4*)(ob + SLEN - 4) = ya;
    }
}

extern "C" void kernel_launch(void* const* d_in, const int* in_sizes, int n_in,
                              void* d_out, int out_size, void* d_ws, size_t ws_size,
                              hipStream_t stream) {
    const float* x     = (const float*)d_in[0];
    const float* W_ih  = (const float*)d_in[1];
    const float* W_hh  = (const float*)d_in[2];
    const float* b_ih  = (const float*)d_in[3];
    const float* b_hh  = (const float*)d_in[4];
    const float* W_lin = (const float*)d_in[5];
    const float* b_lin = (const float*)d_in[6];
    float* out = (float*)d_out;

    const int nblocks = BATCH / 16;   // 256 blocks x 5 waves: full chip
    lstm_fused<<<nblocks, 320, 0, stream>>>(x, W_ih, W_hh, b_ih, b_hh,
                                            W_lin, b_lin, out);
}